// Round 5
// baseline (777.335 us; speedup 1.0000x reference)
//
#include <hip/hip_runtime.h>
#include <hip/hip_bf16.h>

typedef __attribute__((ext_vector_type(8))) short bf16x8;
typedef __attribute__((ext_vector_type(4))) float f32x4;

__device__ __forceinline__ ushort f2bf(float x) {
  unsigned u = __float_as_uint(x);
  u = (u + 0x7FFFu + ((u >> 16) & 1u)) >> 16;
  return (ushort)u;
}

// Kt[o][i] = bf16(K[i][o]);  K: [256][1024] f32, Kt: [1024][256] bf16
__global__ void WV_kconv(const float* __restrict__ K, ushort* __restrict__ Kt) {
  int f = (blockIdx.x * 256 + threadIdx.x) * 4;
  int o = f >> 8, i0 = f & 255;
  ushort4 w;
  w.x = f2bf(K[(size_t)(i0 + 0) * 1024 + o]);
  w.y = f2bf(K[(size_t)(i0 + 1) * 1024 + o]);
  w.z = f2bf(K[(size_t)(i0 + 2) * 1024 + o]);
  w.w = f2bf(K[(size_t)(i0 + 3) * 1024 + o]);
  *reinterpret_cast<ushort4*>(Kt + f) = w;
}

// One block per b. 8 waves x 64. A_b staged to LDS as swizzled bf16.
// Wave w owns o-columns [w*128, w*128+128).
// Register block: 4 i-tiles x 4 o-tiles of 16x16x32 MFMA (64 acc VGPRs).
__global__ __launch_bounds__(512, 1) void WV_main(
    const float* __restrict__ A, const ushort* __restrict__ Kt,
    float* __restrict__ out) {
  __shared__ short As[256 * 256];  // 128 KB bf16, XOR-swizzled rows
  const int b = blockIdx.x;
  const float* Ab = A + (size_t)b * 65536;
  const int t = threadIdx.x;

  // ---- stage A_b: fp32 -> bf16 into LDS, swizzle byte ^= (row&7)<<4 ----
  #pragma unroll
  for (int it = 0; it < 16; ++it) {
    int c = it * 512 + t;  // chunk of 8 floats (16 B bf16)
    int m = c >> 5;        // row 0..255
    int s = c & 31;        // 16B slot within row
    const float4* p = reinterpret_cast<const float4*>(Ab) + c * 2;
    float4 v0 = p[0], v1 = p[1];
    bf16x8 w;
    w[0] = (short)f2bf(v0.x); w[1] = (short)f2bf(v0.y);
    w[2] = (short)f2bf(v0.z); w[3] = (short)f2bf(v0.w);
    w[4] = (short)f2bf(v1.x); w[5] = (short)f2bf(v1.y);
    w[6] = (short)f2bf(v1.z); w[7] = (short)f2bf(v1.w);
    int byteoff = m * 512 + ((s * 16) ^ ((m & 7) << 4));
    *reinterpret_cast<bf16x8*>(reinterpret_cast<char*>(As) + byteoff) = w;
  }
  __syncthreads();

  const int wave = t >> 6, lane = t & 63;
  const int lo = lane & 15;   // row (A) / col (B,D) within tile
  const int hi = lane >> 4;   // 0..3: k-group (A,B) / row-group (D)
  const int wob = wave * 128; // wave's o-strip base

  float oacc[8];
  #pragma unroll
  for (int g = 0; g < 8; ++g) oacc[g] = 0.f;

  #pragma unroll
  for (int og = 0; og < 2; ++og) {
    #pragma unroll
    for (int ig = 0; ig < 4; ++ig) {
      f32x4 acc[4][4];
      #pragma unroll
      for (int a1 = 0; a1 < 4; ++a1)
        #pragma unroll
        for (int a2 = 0; a2 < 4; ++a2)
          acc[a1][a2] = (f32x4){0.f, 0.f, 0.f, 0.f};

      for (int ks = 0; ks < 8; ++ks) {
        const int kk = ks * 32 + hi * 8;  // lane's 8 contiguous k
        bf16x8 Bf[4];
        #pragma unroll
        for (int ot = 0; ot < 4; ++ot) {
          int n = wob + og * 64 + ot * 16 + lo;
          Bf[ot] = *reinterpret_cast<const bf16x8*>(Kt + n * 256 + kk);
        }
        #pragma unroll
        for (int itl = 0; itl < 4; ++itl) {
          int m = ig * 64 + itl * 16 + lo;
          int byteoff = m * 512 + ((kk * 2) ^ ((m & 7) << 4));
          bf16x8 Af = *reinterpret_cast<const bf16x8*>(
              reinterpret_cast<char*>(As) + byteoff);
          #pragma unroll
          for (int ot = 0; ot < 4; ++ot)
            acc[itl][ot] = __builtin_amdgcn_mfma_f32_16x16x32_bf16(
                Af, Bf[ot], acc[itl][ot], 0, 0, 0);
        }
      }

      // epilogue: out[b,o] += sum_i K[i,o]*C[i,o] for this i-range
      #pragma unroll
      for (int itl = 0; itl < 4; ++itl) {
        const int i0 = ig * 64 + itl * 16 + hi * 4;  // lane's 4 D-rows
        #pragma unroll
        for (int ot = 0; ot < 4; ++ot) {
          int n = wob + og * 64 + ot * 16 + lo;
          ushort4 wv = *reinterpret_cast<const ushort4*>(Kt + n * 256 + i0);
          f32x4 a = acc[itl][ot];
          float s = __uint_as_float((unsigned)wv.x << 16) * a[0]
                  + __uint_as_float((unsigned)wv.y << 16) * a[1]
                  + __uint_as_float((unsigned)wv.z << 16) * a[2]
                  + __uint_as_float((unsigned)wv.w << 16) * a[3];
          s += __shfl_xor(s, 16);
          s += __shfl_xor(s, 32);
          oacc[og * 4 + ot] += s;
        }
      }
    }
  }

  if (lane < 16) {
    #pragma unroll
    for (int g = 0; g < 8; ++g) {
      int n = wob + (g >> 2) * 64 + (g & 3) * 16 + lane;
      out[(size_t)b * 1024 + n] = oacc[g];
    }
  }
}

extern "C" void kernel_launch(void* const* d_in, const int* in_sizes, int n_in,
                              void* d_out, int out_size, void* d_ws, size_t ws_size,
                              hipStream_t stream) {
  const float* A = (const float*)d_in[0];   // (256,256,256) f32
  const float* K = (const float*)d_in[1];   // (256,1024)   f32
  float* out = (float*)d_out;               // (256,1024)   f32
  ushort* Kt = (ushort*)d_ws;               // (1024,256)   bf16
  WV_kconv<<<256, 256, 0, stream>>>(K, Kt);
  WV_main<<<256, 512, 0, stream>>>(A, Kt, out);
}

// Round 6
// 105.358 us; speedup vs baseline: 7.3780x; 7.3780x over previous
//
#include <hip/hip_runtime.h>
#include <hip/hip_bf16.h>

typedef __attribute__((ext_vector_type(8))) short bf16x8;
typedef __attribute__((ext_vector_type(4))) float f32x4;

__device__ __forceinline__ ushort f2bf(float x) {
  unsigned u = __float_as_uint(x);
  u = (u + 0x7FFFu + ((u >> 16) & 1u)) >> 16;
  return (ushort)u;
}

// Kt[o][i] = bf16(K[i][o]);  K: [256][1024] f32, Kt: [1024][256] bf16
__global__ void WV_kconv(const float* __restrict__ K, ushort* __restrict__ Kt) {
  int f = (blockIdx.x * 256 + threadIdx.x) * 4;
  int o = f >> 8, i0 = f & 255;
  ushort4 w;
  w.x = f2bf(K[(size_t)(i0 + 0) * 1024 + o]);
  w.y = f2bf(K[(size_t)(i0 + 1) * 1024 + o]);
  w.z = f2bf(K[(size_t)(i0 + 2) * 1024 + o]);
  w.w = f2bf(K[(size_t)(i0 + 3) * 1024 + o]);
  *reinterpret_cast<ushort4*>(Kt + f) = w;
}

// One block per b. 8 waves x 64. A_b staged to LDS as swizzled bf16.
// Wave w owns o-columns [w*128, w*128+128).
// Loop discipline: og/ig/ks are REAL loops (#pragma unroll 1) to bound
// register liveness; only the 4x4 MFMA micro-tile is unrolled.
__global__ __launch_bounds__(512, 1) void WV_main(
    const float* __restrict__ A, const ushort* __restrict__ Kt,
    float* __restrict__ out) {
  __shared__ short As[256 * 256];  // 128 KB bf16, XOR-swizzled rows
  const int b = blockIdx.x;
  const float* Ab = A + (size_t)b * 65536;
  const int t = threadIdx.x;

  // ---- stage A_b: fp32 -> bf16 into LDS, swizzle byte ^= (row&7)<<4 ----
  #pragma unroll 2
  for (int it = 0; it < 16; ++it) {
    int c = it * 512 + t;  // chunk of 8 floats (16 B bf16)
    int m = c >> 5;        // row 0..255
    int s = c & 31;        // 16B slot within row
    const float4* p = reinterpret_cast<const float4*>(Ab) + c * 2;
    float4 v0 = p[0], v1 = p[1];
    bf16x8 w;
    w[0] = (short)f2bf(v0.x); w[1] = (short)f2bf(v0.y);
    w[2] = (short)f2bf(v0.z); w[3] = (short)f2bf(v0.w);
    w[4] = (short)f2bf(v1.x); w[5] = (short)f2bf(v1.y);
    w[6] = (short)f2bf(v1.z); w[7] = (short)f2bf(v1.w);
    int byteoff = m * 512 + ((s * 16) ^ ((m & 7) << 4));
    *reinterpret_cast<bf16x8*>(reinterpret_cast<char*>(As) + byteoff) = w;
  }
  __syncthreads();

  const int wave = t >> 6, lane = t & 63;
  const int lo = lane & 15;   // row (A) / col (B,D) within tile
  const int hi = lane >> 4;   // 0..3: k-group (A,B) / row-group (D)
  const int wob = wave * 128; // wave's o-strip base

  #pragma unroll 1
  for (int og = 0; og < 2; ++og) {
    float oseg[4] = {0.f, 0.f, 0.f, 0.f};  // static-indexed only

    #pragma unroll 1
    for (int ig = 0; ig < 4; ++ig) {
      f32x4 acc[4][4];
      #pragma unroll
      for (int a1 = 0; a1 < 4; ++a1)
        #pragma unroll
        for (int a2 = 0; a2 < 4; ++a2)
          acc[a1][a2] = (f32x4){0.f, 0.f, 0.f, 0.f};

      #pragma unroll 1
      for (int ks = 0; ks < 8; ++ks) {
        const int kk = ks * 32 + hi * 8;  // lane's 8 contiguous k
        bf16x8 Bf[4];
        #pragma unroll
        for (int ot = 0; ot < 4; ++ot) {
          int n = wob + og * 64 + ot * 16 + lo;
          Bf[ot] = *reinterpret_cast<const bf16x8*>(Kt + n * 256 + kk);
        }
        #pragma unroll
        for (int itl = 0; itl < 4; ++itl) {
          int m = ig * 64 + itl * 16 + lo;
          int byteoff = m * 512 + ((kk * 2) ^ ((m & 7) << 4));
          bf16x8 Af = *reinterpret_cast<const bf16x8*>(
              reinterpret_cast<char*>(As) + byteoff);
          #pragma unroll
          for (int ot = 0; ot < 4; ++ot)
            acc[itl][ot] = __builtin_amdgcn_mfma_f32_16x16x32_bf16(
                Af, Bf[ot], acc[itl][ot], 0, 0, 0);
        }
      }

      // epilogue: oseg[ot] += sum over this ig's 64 i-rows
      #pragma unroll
      for (int itl = 0; itl < 4; ++itl) {
        const int i0 = ig * 64 + itl * 16 + hi * 4;  // lane's 4 D-rows
        #pragma unroll
        for (int ot = 0; ot < 4; ++ot) {
          int n = wob + og * 64 + ot * 16 + lo;
          ushort4 wv = *reinterpret_cast<const ushort4*>(Kt + n * 256 + i0);
          f32x4 a = acc[itl][ot];
          float s = __uint_as_float((unsigned)wv.x << 16) * a[0]
                  + __uint_as_float((unsigned)wv.y << 16) * a[1]
                  + __uint_as_float((unsigned)wv.z << 16) * a[2]
                  + __uint_as_float((unsigned)wv.w << 16) * a[3];
          s += __shfl_xor(s, 16);
          s += __shfl_xor(s, 32);
          oseg[ot] += s;
        }
      }
    }

    if (lane < 16) {
      #pragma unroll
      for (int ot = 0; ot < 4; ++ot)
        out[(size_t)b * 1024 + wob + og * 64 + ot * 16 + lane] = oseg[ot];
    }
  }
}

extern "C" void kernel_launch(void* const* d_in, const int* in_sizes, int n_in,
                              void* d_out, int out_size, void* d_ws, size_t ws_size,
                              hipStream_t stream) {
  const float* A = (const float*)d_in[0];   // (256,256,256) f32
  const float* K = (const float*)d_in[1];   // (256,1024)   f32
  float* out = (float*)d_out;               // (256,1024)   f32
  ushort* Kt = (ushort*)d_ws;               // (1024,256)   bf16
  WV_kconv<<<256, 256, 0, stream>>>(K, Kt);
  WV_main<<<256, 512, 0, stream>>>(A, Kt, out);
}